// Round 11
// baseline (200.617 us; speedup 1.0000x reference)
//
#include <hip/hip_runtime.h>
#include <math.h>

#define NN 20000
#define NE 640000
#define D  128
#define NSLICE 2500        // NN / 8 XCDs
#define SUBSEG 40          // per-(node, src-quartile) sub-segment depth
#define SEGSTRIDE 160      // 4 * SUBSEG entries per node
#define CHUNK 1000         // edges per fill chunk (640*1000 = NE)

typedef __attribute__((ext_vector_type(8))) short short8;
typedef __attribute__((ext_vector_type(4))) float floatx4;

static __device__ __forceinline__ unsigned short f2bf(float f) {
    union { float f; unsigned int u; } v; v.f = f;
    unsigned int u = v.u;
    u += 0x7fff + ((u >> 16) & 1);   // round-to-nearest-even
    return (unsigned short)(u >> 16);
}
static __device__ __forceinline__ unsigned int pack2bf(float a, float b) {
    return (unsigned int)f2bf(a) | ((unsigned int)f2bf(b) << 16);
}
static __device__ __forceinline__ float bf_lo(unsigned int u) {
    union { unsigned int i; float f; } v; v.i = u << 16; return v.f;
}
static __device__ __forceinline__ float bf_hi(unsigned int u) {
    union { unsigned int i; float f; } v; v.i = u & 0xffff0000u; return v.f;
}
static __device__ __forceinline__ float sigm(float x) { return 1.f / (1.f + __expf(-x)); }
static __device__ __forceinline__ float tanhx(float x) { return 1.f - 2.f / (__expf(2.f * x) + 1.f); }

static __device__ __forceinline__ void load_lds16(const void* g, void* l) {
    __builtin_amdgcn_global_load_lds(
        (const __attribute__((address_space(1))) unsigned int*)g,
        (__attribute__((address_space(3))) unsigned int*)l, 16, 0, 0);
}

// Fused prep + CSR fill. R11: __launch_bounds__(256, 4) — the R1-R10
// builds compiled to VGPR_Count=16 (max-occupancy target), which
// SERIALIZED the int4 edge loads and float4 X/H loads (2-3 outstanding
// per wave instead of the written 8+). min-4-waves/SIMD raises the VGPR
// budget to 128 so the batched loads stay live -> true MLP. 4 blocks/CU
// instead of 8, but ~4x the outstanding loads per wave.
// Src-quartile-binned bump allocation (q = src/5000, SUBSEG deep); X/H
// bf16 pack; coalesced weight transpose; bias fuse; XCD-sliced fill.
// Wsz layout (shorts): idx = ci*16384 + jg*4096 + col*8 + off, k = ci*32+jg*8+off.
__global__ void __launch_bounds__(256, 4)
prep_fill_kernel(const int* __restrict__ src, const int* __restrict__ dst,
                 const float* __restrict__ ew, int* __restrict__ cnt4,
                 unsigned int* __restrict__ s_p,
                 const float4* __restrict__ X4, const float4* __restrict__ H4,
                 unsigned int* __restrict__ XH32,
                 const float* __restrict__ Wx_l, const float* __restrict__ Wx_r,
                 const float* __restrict__ Wh_l, const float* __restrict__ Wh_r,
                 const float* __restrict__ bx, const float* __restrict__ bh,
                 const float* __restrict__ bg,
                 unsigned short* __restrict__ Wsz, float* __restrict__ bias) {
    int tid = threadIdx.x, b = blockIdx.x;       // 5120 blocks x 256 threads

    int chunk = b >> 3, s = b & 7;
    int lo = s * NSLICE, hi = lo + NSLICE;
    int4 d4, sr4; float4 w4;
    bool fill = (tid < 250);
    if (fill) {
        int e0 = chunk * CHUNK + tid * 4;
        d4  = *(const int4*)(dst + e0);
        sr4 = *(const int4*)(src + e0);
        w4  = *(const float4*)(ew + e0);
    }

    if (b < 2560) {
        int t = b * 256 + tid;
        if (t < NE) {
            float4 x = X4[t];
            float4 h = H4[t];
            int n = t >> 5, q = t & 31;
            unsigned int* row = XH32 + n * 128;
            row[2 * q]          = pack2bf(x.x, x.y);
            row[2 * q + 1]      = pack2bf(x.z, x.w);
            row[64 + 2 * q]     = pack2bf(h.x, h.y);
            row[64 + 2 * q + 1] = pack2bf(h.z, h.w);
        }
    } else if (b < 2816) {
        int t = (b - 2560) * 256 + tid;      // < 65536
        int row = t >> 5;                    // row = g*512 + k
        int g = row >> 9, k = row & 511;
        int o = (t & 31) * 4;
        const float* Wb; int kk;
        if (k < 128)      { Wb = Wx_l; kk = k; }
        else if (k < 256) { Wb = Wx_r; kk = k - 128; }
        else if (k < 384) { Wb = Wh_l; kk = k - 256; }
        else              { Wb = Wh_r; kk = k - 384; }
        float4 w = *(const float4*)(Wb + g * 16384 + kk * 128 + o);
        int ci = k >> 5, jg = (k >> 3) & 3, off = k & 7;
        unsigned short* wp = Wsz + ci * 16384 + jg * 4096 + (g * 128 + o) * 8 + off;
        wp[0]  = f2bf(w.x);
        wp[8]  = f2bf(w.y);
        wp[16] = f2bf(w.z);
        wp[24] = f2bf(w.w);
        if (k == 0) {
            int j0 = g * 128 + o;
#pragma unroll
            for (int i = 0; i < 4; ++i)
                bias[j0 + i] = bx[j0 + i] + bh[j0 + i] + bg[j0 + i];
        }
    }

    if (fill) {
        int dv[4] = {d4.x, d4.y, d4.z, d4.w};
        int sv[4] = {sr4.x, sr4.y, sr4.z, sr4.w};
        float wv[4] = {w4.x, w4.y, w4.z, w4.w};
#pragma unroll
        for (int k = 0; k < 4; ++k) {
            int d = dv[k];
            if (d >= lo && d < hi) {
                int q = (int)((unsigned)sv[k] / 5000u);   // src window 0..3
                int p = atomicAdd(&cnt4[d * 4 + q], 1);
                if (p < SUBSEG)
                    s_p[d * SEGSTRIDE + q * SUBSEG + p] =
                        (unsigned int)sv[k] | ((unsigned int)f2bf(wv[k]) << 16);
            }
        }
    }
}

// Aggregation. R11: __launch_bounds__(256, 4) — previous builds compiled
// to VGPR_Count=16, which cannot hold the declared u[8] gather batch
// (16 VGPR by itself) -> the compiler serialized the gathers to 2-3
// outstanding and every "N in flight" comment was fiction. 128-VGPR
// budget lets the 8-deep batch actually fly. 4 blocks/CU x 4 waves x
// 8 outstanding = 128 in-flight gathers/CU (was ~64 serialized-ish).
// Otherwise unchanged: 4 source-window passes (2.56 MB window fits
// per-XCD L2), scalarized seg/weight/address via readfirstlane(n).
__global__ void __launch_bounds__(256, 4)
aggregate_kernel(const uint2* __restrict__ XH64,
                 const int* __restrict__ cnt4,
                 const unsigned int* __restrict__ s_p,
                 uint2* __restrict__ AGG64) {
    int wv = threadIdx.x >> 6, lane = threadIdx.x & 63;
    int b = blockIdx.x;                 // 0..4999
    int s = b & 7, j = b >> 3;          // j: 0..624
    int n = __builtin_amdgcn_readfirstlane(s * NSLICE + j * 4 + wv);
    int c0 = cnt4[n * 4 + 0];           // uniform -> scalar loads
    int c1 = cnt4[n * 4 + 1];
    int c2 = cnt4[n * 4 + 2];
    int c3 = cnt4[n * 4 + 3];
    int deg = c0 + c1 + c2 + c3;
    const unsigned int* segbase = s_p + (size_t)n * SEGSTRIDE;
    float a0 = 0.f, a1 = 0.f, a2 = 0.f, a3 = 0.f;

#pragma unroll
    for (int p = 0; p < 4; ++p) {
        int c = (p == 0) ? c0 : (p == 1) ? c1 : (p == 2) ? c2 : c3;
        int m = (c < SUBSEG) ? c : SUBSEG;
        const unsigned int* seg = segbase + p * SUBSEG;
        int i = 0;
        for (; i + 8 <= m; i += 8) {
            unsigned int e[8];
            uint2 u[8];
#pragma unroll
            for (int k = 0; k < 8; ++k) e[k] = seg[i + k];   // scalar
#pragma unroll
            for (int k = 0; k < 8; ++k)
                u[k] = XH64[(size_t)(e[k] & 0xffff) * 64 + lane];
#pragma unroll
            for (int k = 0; k < 8; ++k) {
                float w = __int_as_float(e[k] & 0xffff0000u);
                a0 += bf_lo(u[k].x) * w;
                a1 += bf_hi(u[k].x) * w;
                a2 += bf_lo(u[k].y) * w;
                a3 += bf_hi(u[k].y) * w;
            }
        }
        for (; i + 4 <= m; i += 4) {
            unsigned int e[4];
            uint2 u[4];
#pragma unroll
            for (int k = 0; k < 4; ++k) e[k] = seg[i + k];
#pragma unroll
            for (int k = 0; k < 4; ++k)
                u[k] = XH64[(size_t)(e[k] & 0xffff) * 64 + lane];
#pragma unroll
            for (int k = 0; k < 4; ++k) {
                float w = __int_as_float(e[k] & 0xffff0000u);
                a0 += bf_lo(u[k].x) * w;
                a1 += bf_hi(u[k].x) * w;
                a2 += bf_lo(u[k].y) * w;
                a3 += bf_hi(u[k].y) * w;
            }
        }
        for (; i < m; ++i) {
            unsigned int e = seg[i];
            float w = __int_as_float(e & 0xffff0000u);
            uint2 u = XH64[(size_t)(e & 0xffff) * 64 + lane];
            a0 += bf_lo(u.x) * w;
            a1 += bf_hi(u.x) * w;
            a2 += bf_lo(u.y) * w;
            a3 += bf_hi(u.y) * w;
        }
    }

    float inv = (deg > 0) ? 1.0f / (float)deg : 1.0f;
    uint2 r;
    r.x = pack2bf(a0 * inv, a1 * inv);
    r.y = pack2bf(a2 * inv, a3 * inv);
    AGG64[(size_t)n * 64 + lane] = r;
}

// R10 GEMM + peephole-LSTM (unchanged — control). M=64 tile + one-shot
// LDS A-panels staged via global_load_lds with pre-swizzled source
// offsets; B frags direct from L2; 1-deep prefetch; in-register LSTM
// epilogue; 626 blocks = 313 m-tiles x 2 column-halves.
__global__ void __launch_bounds__(256)
gemm_lstm_kernel(const unsigned short* __restrict__ XH,
                 const unsigned short* __restrict__ AGG,
                 const unsigned short* __restrict__ Wsz,
                 const float* __restrict__ bias,
                 const float* __restrict__ wc,
                 const float* __restrict__ C,
                 float* __restrict__ out) {
    __shared__ __align__(16) char sA[65536];   // [0,32K)=XH panel, [32K,64K)=AGG

    int tid = threadIdx.x;
    int wv = tid >> 6, lane = tid & 63;
    int lm = lane & 15, lq = lane >> 4;
    int bid = blockIdx.x;                 // 626 = 313 m-tiles x 2 halves
    int m0 = (bid >> 1) * 64;
    int hb = (bid & 1) * 512;             // half-offset in shorts (64 cols * 8)

    // ---- stage A panels (once): wave wv stages local rows [wv*16, wv*16+16)
    // of both panels; source offset pre-swizzled so reads use ofs ^ ((row&7)<<4).
    {
        int lrow = (lane >> 5);                       // 0/1 within pair
#pragma unroll
        for (int j = 0; j < 8; ++j) {
            int r0 = wv * 16 + j * 2;                 // pair base row (even)
            int rw = r0 + lrow;                       // this lane's row
            int go = ((lane & 31) * 16) ^ ((rw & 7) << 4);
            load_lds16(XH + (size_t)(m0 + rw) * 256 + (go >> 1),
                       sA + r0 * 512);
            load_lds16(AGG + (size_t)(m0 + rw) * 256 + (go >> 1),
                       sA + 32768 + r0 * 512);
        }
    }

    floatx4 acc[4][4];
#pragma unroll
    for (int mt = 0; mt < 4; ++mt)
#pragma unroll
        for (int g = 0; g < 4; ++g) acc[mt][g] = (floatx4)(0.f);

    // B base: col = g*128 + hb/8 + wv*16 + lm, k-group jg = lq
    const unsigned short* wB = Wsz + lq * 4096 + hb + ((wv << 4) + lm) * 8;

    // preload B for it=0 (ci=4) — independent of LDS, overlaps staging
    short8 cb0 = *(const short8*)(wB + 4 * 16384);
    short8 cb1 = *(const short8*)(wB + 4 * 16384 + 1024);
    short8 cb2 = *(const short8*)(wB + 4 * 16384 + 2048);
    short8 cb3 = *(const short8*)(wB + 4 * 16384 + 3072);

    __syncthreads();   // drains staging vmcnt; A panels ready

    int swr = (lm & 7) << 4;
    for (int it = 0; it < 16; ++it) {
        short8 nb0, nb1, nb2, nb3;
        if (it < 15) {
            int itn = it + 1;
            int ci = (itn < 8) ? (itn + 4 + (itn & 4)) : ((itn - 8) + ((itn - 8) & 4));
            const unsigned short* wb2 = wB + ci * 16384;
            nb0 = *(const short8*)(wb2);
            nb1 = *(const short8*)(wb2 + 1024);
            nb2 = *(const short8*)(wb2 + 2048);
            nb3 = *(const short8*)(wb2 + 3072);
        }
        int pbase = (it < 8) ? 0 : 32768;
        int koff = (it & 7) * 64 + lq * 16;
#pragma unroll
        for (int mt = 0; mt < 4; ++mt) {
            int b0 = pbase + (mt * 16 + lm) * 512 + (koff ^ swr);
            short8 a = *(const short8*)(sA + b0);
            acc[mt][0] = __builtin_amdgcn_mfma_f32_16x16x32_bf16(a, cb0, acc[mt][0], 0, 0, 0);
            acc[mt][1] = __builtin_amdgcn_mfma_f32_16x16x32_bf16(a, cb1, acc[mt][1], 0, 0, 0);
            acc[mt][2] = __builtin_amdgcn_mfma_f32_16x16x32_bf16(a, cb2, acc[mt][2], 0, 0, 0);
            acc[mt][3] = __builtin_amdgcn_mfma_f32_16x16x32_bf16(a, cb3, acc[mt][3], 0, 0, 0);
        }
        cb0 = nb0; cb1 = nb1; cb2 = nb2; cb3 = nb3;
    }

    // ---- LSTM epilogue (in-register) ----
    int cg0 = (hb >> 3) + (wv << 4) + lm;
    float bG[4], wP[3];
#pragma unroll
    for (int g = 0; g < 4; ++g) bG[g] = bias[(g << 7) + cg0];
#pragma unroll
    for (int j = 0; j < 3; ++j) wP[j] = wc[j * 128 + cg0];

#pragma unroll
    for (int mt = 0; mt < 4; ++mt)
#pragma unroll
        for (int r = 0; r < 4; ++r) {
            int row = m0 + mt * 16 + lq * 4 + r;
            if (row < NN) {
                float c = C[(size_t)row * D + cg0];
                float pi = acc[mt][0][r] + bG[0] + wP[0] * c;
                float pf = acc[mt][1][r] + bG[1] + wP[1] * c;
                float pt = acc[mt][2][r] + bG[2];
                float po = acc[mt][3][r] + bG[3];
                float I = sigm(pi);
                float F = sigm(pf);
                float T = tanhx(pt);
                float cn = F * c + I * T;
                float O = sigm(po + wP[2] * cn);
                out[(size_t)row * D + cg0] = O * tanhx(cn);
                out[(size_t)NN * D + (size_t)row * D + cg0] = cn;
            }
        }
}

extern "C" void kernel_launch(void* const* d_in, const int* in_sizes, int n_in,
                              void* d_out, int out_size, void* d_ws, size_t ws_size,
                              hipStream_t stream) {
    const float* X  = (const float*)d_in[0];
    const int* ei   = (const int*)d_in[1];
    const float* ew = (const float*)d_in[2];
    const float* H  = (const float*)d_in[3];
    const float* C  = (const float*)d_in[4];
    const float* Wx_l = (const float*)d_in[5];
    const float* Wx_r = (const float*)d_in[6];
    const float* bx   = (const float*)d_in[7];
    const float* Wh_l = (const float*)d_in[8];
    const float* Wh_r = (const float*)d_in[9];
    const float* bh   = (const float*)d_in[10];
    const float* wc   = (const float*)d_in[11];
    const float* bg   = (const float*)d_in[12];
    float* out = (float*)d_out;

    const int* src = ei;
    const int* dst = ei + NE;

    // workspace layout (16B aligned), ~34.1 MB
    char* ws = (char*)d_ws;
    int* cnt4 = (int*)(ws + 0);                               //    320,000 B
    unsigned int* s_p = (unsigned int*)(ws + 320128);         // 12,800,000 B
    unsigned short* XH  = (unsigned short*)(ws + 13120128);   // 10,240,000 B
    unsigned short* AGG = (unsigned short*)(ws + 23360128);   // 10,240,000 B
    unsigned short* Wsz = (unsigned short*)(ws + 33600128);   //    524,288 B
    float* bias = (float*)(ws + 34124416);                    //      2,048 B

    hipMemsetAsync(cnt4, 0, NN * 4 * sizeof(int), stream);
    prep_fill_kernel<<<5120, 256, 0, stream>>>(src, dst, ew, cnt4, s_p,
                                               (const float4*)X, (const float4*)H,
                                               (unsigned int*)XH,
                                               Wx_l, Wx_r, Wh_l, Wh_r,
                                               bx, bh, bg, Wsz, bias);
    aggregate_kernel<<<NN / 4, 256, 0, stream>>>((const uint2*)XH, cnt4, s_p,
                                                 (uint2*)AGG);
    gemm_lstm_kernel<<<626, 256, 0, stream>>>(XH, AGG, Wsz, bias, wc, C, out);
}

// Round 12
// 200.408 us; speedup vs baseline: 1.0010x; 1.0010x over previous
//
#include <hip/hip_runtime.h>
#include <math.h>

#define NN 20000
#define NE 640000
#define D  128
#define NSLICE 2500        // NN / 8 XCDs
#define SUBSEG 40          // per-(node, src-quartile) sub-segment depth
#define SEGSTRIDE 160      // 4 * SUBSEG entries per node
#define CHUNK 1000         // edges per fill chunk (640*1000 = NE)

typedef __attribute__((ext_vector_type(8))) short short8;
typedef __attribute__((ext_vector_type(4))) float floatx4;

static __device__ __forceinline__ unsigned short f2bf(float f) {
    union { float f; unsigned int u; } v; v.f = f;
    unsigned int u = v.u;
    u += 0x7fff + ((u >> 16) & 1);   // round-to-nearest-even
    return (unsigned short)(u >> 16);
}
static __device__ __forceinline__ unsigned int pack2bf(float a, float b) {
    return (unsigned int)f2bf(a) | ((unsigned int)f2bf(b) << 16);
}
static __device__ __forceinline__ float bf_lo(unsigned int u) {
    union { unsigned int i; float f; } v; v.i = u << 16; return v.f;
}
static __device__ __forceinline__ float bf_hi(unsigned int u) {
    union { unsigned int i; float f; } v; v.i = u & 0xffff0000u; return v.f;
}
static __device__ __forceinline__ float sigm(float x) { return 1.f / (1.f + __expf(-x)); }
static __device__ __forceinline__ float tanhx(float x) { return 1.f - 2.f / (__expf(2.f * x) + 1.f); }

static __device__ __forceinline__ void load_lds16(const void* g, void* l) {
    __builtin_amdgcn_global_load_lds(
        (const __attribute__((address_space(1))) unsigned int*)g,
        (__attribute__((address_space(3))) unsigned int*)l, 16, 0, 0);
}

// Fused prep + CSR fill (R10 form — control; R11's launch_bounds(256,4)
// reverted: measured no effect). Src-quartile-binned bump allocation
// (q = src/5000, SUBSEG deep); X/H bf16 pack; coalesced weight transpose;
// bias fuse; XCD-sliced fill.
// Wsz layout (shorts): idx = ci*16384 + jg*4096 + col*8 + off, k = ci*32+jg*8+off.
__global__ void __launch_bounds__(256)
prep_fill_kernel(const int* __restrict__ src, const int* __restrict__ dst,
                 const float* __restrict__ ew, int* __restrict__ cnt4,
                 unsigned int* __restrict__ s_p,
                 const float4* __restrict__ X4, const float4* __restrict__ H4,
                 unsigned int* __restrict__ XH32,
                 const float* __restrict__ Wx_l, const float* __restrict__ Wx_r,
                 const float* __restrict__ Wh_l, const float* __restrict__ Wh_r,
                 const float* __restrict__ bx, const float* __restrict__ bh,
                 const float* __restrict__ bg,
                 unsigned short* __restrict__ Wsz, float* __restrict__ bias) {
    int tid = threadIdx.x, b = blockIdx.x;       // 5120 blocks x 256 threads

    int chunk = b >> 3, s = b & 7;
    int lo = s * NSLICE, hi = lo + NSLICE;
    int4 d4, sr4; float4 w4;
    bool fill = (tid < 250);
    if (fill) {
        int e0 = chunk * CHUNK + tid * 4;
        d4  = *(const int4*)(dst + e0);
        sr4 = *(const int4*)(src + e0);
        w4  = *(const float4*)(ew + e0);
    }

    if (b < 2560) {
        int t = b * 256 + tid;
        if (t < NE) {
            float4 x = X4[t];
            float4 h = H4[t];
            int n = t >> 5, q = t & 31;
            unsigned int* row = XH32 + n * 128;
            row[2 * q]          = pack2bf(x.x, x.y);
            row[2 * q + 1]      = pack2bf(x.z, x.w);
            row[64 + 2 * q]     = pack2bf(h.x, h.y);
            row[64 + 2 * q + 1] = pack2bf(h.z, h.w);
        }
    } else if (b < 2816) {
        int t = (b - 2560) * 256 + tid;      // < 65536
        int row = t >> 5;                    // row = g*512 + k
        int g = row >> 9, k = row & 511;
        int o = (t & 31) * 4;
        const float* Wb; int kk;
        if (k < 128)      { Wb = Wx_l; kk = k; }
        else if (k < 256) { Wb = Wx_r; kk = k - 128; }
        else if (k < 384) { Wb = Wh_l; kk = k - 256; }
        else              { Wb = Wh_r; kk = k - 384; }
        float4 w = *(const float4*)(Wb + g * 16384 + kk * 128 + o);
        int ci = k >> 5, jg = (k >> 3) & 3, off = k & 7;
        unsigned short* wp = Wsz + ci * 16384 + jg * 4096 + (g * 128 + o) * 8 + off;
        wp[0]  = f2bf(w.x);
        wp[8]  = f2bf(w.y);
        wp[16] = f2bf(w.z);
        wp[24] = f2bf(w.w);
        if (k == 0) {
            int j0 = g * 128 + o;
#pragma unroll
            for (int i = 0; i < 4; ++i)
                bias[j0 + i] = bx[j0 + i] + bh[j0 + i] + bg[j0 + i];
        }
    }

    if (fill) {
        int dv[4] = {d4.x, d4.y, d4.z, d4.w};
        int sv[4] = {sr4.x, sr4.y, sr4.z, sr4.w};
        float wv[4] = {w4.x, w4.y, w4.z, w4.w};
#pragma unroll
        for (int k = 0; k < 4; ++k) {
            int d = dv[k];
            if (d >= lo && d < hi) {
                int q = (int)((unsigned)sv[k] / 5000u);   // src window 0..3
                int p = atomicAdd(&cnt4[d * 4 + q], 1);
                if (p < SUBSEG)
                    s_p[d * SEGSTRIDE + q * SUBSEG + p] =
                        (unsigned int)sv[k] | ((unsigned int)f2bf(wv[k]) << 16);
            }
        }
    }
}

// R12 aggregation: PAIRED uint4 row-gathers — 4 line-requests/edge, was 8.
// Session-wide counter fact: our kernels all plateau at 1.1-1.25 TB/s
// effective while the harness poison fill hits 6.2 TB/s at 8% occupancy —
// the discriminator is requests-per-byte, not occupancy. Old agg: one
// 512 B row per instruction (uint2/lane) = 8 line-req/edge, ~5.1M total.
// New: lanes 0-31 read row e[2k] (uint4, 32x16 B = 512 B), lanes 32-63
// read row e[2k+1] -> one instruction covers TWO edges. Same bytes, half
// the requests, and the 8-edge unroll needs only 4 in-flight loads (16
// VGPR) -> 2x edges in flight at any register budget.
// Epilogue: 8 shfl_xor(...,32) even/odd reduce + half-wave uint4 store.
// Unchanged: scalarized seg reads via readfirstlane(n), 4 source-window
// L2 passes, XCD-sliced block->node mapping, output layout. f32 sum order
// changes only between even/odd partials (<< bf16 quant; absmax stable
// across 4 prior reorders).
__global__ void __launch_bounds__(256)
aggregate_kernel(const unsigned short* __restrict__ XH,
                 const int* __restrict__ cnt4,
                 const unsigned int* __restrict__ s_p,
                 unsigned short* __restrict__ AGG) {
    int wv = threadIdx.x >> 6, lane = threadIdx.x & 63;
    int half = lane >> 5, hl = lane & 31;
    int b = blockIdx.x;                 // 0..4999
    int s = b & 7, j = b >> 3;          // j: 0..624
    int n = __builtin_amdgcn_readfirstlane(s * NSLICE + j * 4 + wv);
    int c0 = cnt4[n * 4 + 0];           // uniform -> scalar loads
    int c1 = cnt4[n * 4 + 1];
    int c2 = cnt4[n * 4 + 2];
    int c3 = cnt4[n * 4 + 3];
    int deg = c0 + c1 + c2 + c3;
    const unsigned int* segbase = s_p + (size_t)n * SEGSTRIDE;
    const uint4* xb = (const uint4*)XH;     // row r: xb + r*32; lane adds hl

    float a0 = 0.f, a1 = 0.f, a2 = 0.f, a3 = 0.f;
    float a4 = 0.f, a5 = 0.f, a6 = 0.f, a7 = 0.f;

#pragma unroll
    for (int p = 0; p < 4; ++p) {
        int c = (p == 0) ? c0 : (p == 1) ? c1 : (p == 2) ? c2 : c3;
        int m = (c < SUBSEG) ? c : SUBSEG;
        const unsigned int* seg = segbase + p * SUBSEG;
        int i = 0;
        for (; i + 8 <= m; i += 8) {        // 4 paired loads in flight
            unsigned int e[8];
#pragma unroll
            for (int k = 0; k < 8; ++k) e[k] = seg[i + k];   // scalar
            unsigned int ep[4];
            uint4 v[4];
#pragma unroll
            for (int k = 0; k < 4; ++k) {
                ep[k] = e[k * 2 + half];                     // even/odd select
                v[k] = xb[(size_t)(ep[k] & 0xffff) * 32 + hl];
            }
#pragma unroll
            for (int k = 0; k < 4; ++k) {
                float w = __int_as_float(ep[k] & 0xffff0000u);
                a0 += bf_lo(v[k].x) * w; a1 += bf_hi(v[k].x) * w;
                a2 += bf_lo(v[k].y) * w; a3 += bf_hi(v[k].y) * w;
                a4 += bf_lo(v[k].z) * w; a5 += bf_hi(v[k].z) * w;
                a6 += bf_lo(v[k].w) * w; a7 += bf_hi(v[k].w) * w;
            }
        }
        for (; i + 2 <= m; i += 2) {
            unsigned int ep = seg[i + half];
            uint4 v = xb[(size_t)(ep & 0xffff) * 32 + hl];
            float w = __int_as_float(ep & 0xffff0000u);
            a0 += bf_lo(v.x) * w; a1 += bf_hi(v.x) * w;
            a2 += bf_lo(v.y) * w; a3 += bf_hi(v.y) * w;
            a4 += bf_lo(v.z) * w; a5 += bf_hi(v.z) * w;
            a6 += bf_lo(v.w) * w; a7 += bf_hi(v.w) * w;
        }
        if (i < m) {                          // odd leftover: half-1 adds 0
            unsigned int ep = seg[i];
            uint4 v = xb[(size_t)(ep & 0xffff) * 32 + hl];
            float w = half ? 0.f : __int_as_float(ep & 0xffff0000u);
            a0 += bf_lo(v.x) * w; a1 += bf_hi(v.x) * w;
            a2 += bf_lo(v.y) * w; a3 += bf_hi(v.y) * w;
            a4 += bf_lo(v.z) * w; a5 += bf_hi(v.z) * w;
            a6 += bf_lo(v.w) * w; a7 += bf_hi(v.w) * w;
        }
    }

    // even/odd partial reduce across the two 32-lane halves
    a0 += __shfl_xor(a0, 32, 64); a1 += __shfl_xor(a1, 32, 64);
    a2 += __shfl_xor(a2, 32, 64); a3 += __shfl_xor(a3, 32, 64);
    a4 += __shfl_xor(a4, 32, 64); a5 += __shfl_xor(a5, 32, 64);
    a6 += __shfl_xor(a6, 32, 64); a7 += __shfl_xor(a7, 32, 64);

    if (half == 0) {
        float inv = (deg > 0) ? 1.0f / (float)deg : 1.0f;
        uint4 r;
        r.x = pack2bf(a0 * inv, a1 * inv);
        r.y = pack2bf(a2 * inv, a3 * inv);
        r.z = pack2bf(a4 * inv, a5 * inv);
        r.w = pack2bf(a6 * inv, a7 * inv);
        *((uint4*)AGG + (size_t)n * 32 + hl) = r;
    }
}

// R10 GEMM + peephole-LSTM (unchanged — control). M=64 tile + one-shot
// LDS A-panels staged via global_load_lds with pre-swizzled source
// offsets; B frags direct from L2; 1-deep prefetch; in-register LSTM
// epilogue; 626 blocks = 313 m-tiles x 2 column-halves.
__global__ void __launch_bounds__(256)
gemm_lstm_kernel(const unsigned short* __restrict__ XH,
                 const unsigned short* __restrict__ AGG,
                 const unsigned short* __restrict__ Wsz,
                 const float* __restrict__ bias,
                 const float* __restrict__ wc,
                 const float* __restrict__ C,
                 float* __restrict__ out) {
    __shared__ __align__(16) char sA[65536];   // [0,32K)=XH panel, [32K,64K)=AGG

    int tid = threadIdx.x;
    int wv = tid >> 6, lane = tid & 63;
    int lm = lane & 15, lq = lane >> 4;
    int bid = blockIdx.x;                 // 626 = 313 m-tiles x 2 halves
    int m0 = (bid >> 1) * 64;
    int hb = (bid & 1) * 512;             // half-offset in shorts (64 cols * 8)

    // ---- stage A panels (once): wave wv stages local rows [wv*16, wv*16+16)
    // of both panels; source offset pre-swizzled so reads use ofs ^ ((row&7)<<4).
    {
        int lrow = (lane >> 5);                       // 0/1 within pair
#pragma unroll
        for (int j = 0; j < 8; ++j) {
            int r0 = wv * 16 + j * 2;                 // pair base row (even)
            int rw = r0 + lrow;                       // this lane's row
            int go = ((lane & 31) * 16) ^ ((rw & 7) << 4);
            load_lds16(XH + (size_t)(m0 + rw) * 256 + (go >> 1),
                       sA + r0 * 512);
            load_lds16(AGG + (size_t)(m0 + rw) * 256 + (go >> 1),
                       sA + 32768 + r0 * 512);
        }
    }

    floatx4 acc[4][4];
#pragma unroll
    for (int mt = 0; mt < 4; ++mt)
#pragma unroll
        for (int g = 0; g < 4; ++g) acc[mt][g] = (floatx4)(0.f);

    // B base: col = g*128 + hb/8 + wv*16 + lm, k-group jg = lq
    const unsigned short* wB = Wsz + lq * 4096 + hb + ((wv << 4) + lm) * 8;

    // preload B for it=0 (ci=4) — independent of LDS, overlaps staging
    short8 cb0 = *(const short8*)(wB + 4 * 16384);
    short8 cb1 = *(const short8*)(wB + 4 * 16384 + 1024);
    short8 cb2 = *(const short8*)(wB + 4 * 16384 + 2048);
    short8 cb3 = *(const short8*)(wB + 4 * 16384 + 3072);

    __syncthreads();   // drains staging vmcnt; A panels ready

    int swr = (lm & 7) << 4;
    for (int it = 0; it < 16; ++it) {
        short8 nb0, nb1, nb2, nb3;
        if (it < 15) {
            int itn = it + 1;
            int ci = (itn < 8) ? (itn + 4 + (itn & 4)) : ((itn - 8) + ((itn - 8) & 4));
            const unsigned short* wb2 = wB + ci * 16384;
            nb0 = *(const short8*)(wb2);
            nb1 = *(const short8*)(wb2 + 1024);
            nb2 = *(const short8*)(wb2 + 2048);
            nb3 = *(const short8*)(wb2 + 3072);
        }
        int pbase = (it < 8) ? 0 : 32768;
        int koff = (it & 7) * 64 + lq * 16;
#pragma unroll
        for (int mt = 0; mt < 4; ++mt) {
            int b0 = pbase + (mt * 16 + lm) * 512 + (koff ^ swr);
            short8 a = *(const short8*)(sA + b0);
            acc[mt][0] = __builtin_amdgcn_mfma_f32_16x16x32_bf16(a, cb0, acc[mt][0], 0, 0, 0);
            acc[mt][1] = __builtin_amdgcn_mfma_f32_16x16x32_bf16(a, cb1, acc[mt][1], 0, 0, 0);
            acc[mt][2] = __builtin_amdgcn_mfma_f32_16x16x32_bf16(a, cb2, acc[mt][2], 0, 0, 0);
            acc[mt][3] = __builtin_amdgcn_mfma_f32_16x16x32_bf16(a, cb3, acc[mt][3], 0, 0, 0);
        }
        cb0 = nb0; cb1 = nb1; cb2 = nb2; cb3 = nb3;
    }

    // ---- LSTM epilogue (in-register) ----
    int cg0 = (hb >> 3) + (wv << 4) + lm;
    float bG[4], wP[3];
#pragma unroll
    for (int g = 0; g < 4; ++g) bG[g] = bias[(g << 7) + cg0];
#pragma unroll
    for (int j = 0; j < 3; ++j) wP[j] = wc[j * 128 + cg0];

#pragma unroll
    for (int mt = 0; mt < 4; ++mt)
#pragma unroll
        for (int r = 0; r < 4; ++r) {
            int row = m0 + mt * 16 + lq * 4 + r;
            if (row < NN) {
                float c = C[(size_t)row * D + cg0];
                float pi = acc[mt][0][r] + bG[0] + wP[0] * c;
                float pf = acc[mt][1][r] + bG[1] + wP[1] * c;
                float pt = acc[mt][2][r] + bG[2];
                float po = acc[mt][3][r] + bG[3];
                float I = sigm(pi);
                float F = sigm(pf);
                float T = tanhx(pt);
                float cn = F * c + I * T;
                float O = sigm(po + wP[2] * cn);
                out[(size_t)row * D + cg0] = O * tanhx(cn);
                out[(size_t)NN * D + (size_t)row * D + cg0] = cn;
            }
        }
}

extern "C" void kernel_launch(void* const* d_in, const int* in_sizes, int n_in,
                              void* d_out, int out_size, void* d_ws, size_t ws_size,
                              hipStream_t stream) {
    const float* X  = (const float*)d_in[0];
    const int* ei   = (const int*)d_in[1];
    const float* ew = (const float*)d_in[2];
    const float* H  = (const float*)d_in[3];
    const float* C  = (const float*)d_in[4];
    const float* Wx_l = (const float*)d_in[5];
    const float* Wx_r = (const float*)d_in[6];
    const float* bx   = (const float*)d_in[7];
    const float* Wh_l = (const float*)d_in[8];
    const float* Wh_r = (const float*)d_in[9];
    const float* bh   = (const float*)d_in[10];
    const float* wc   = (const float*)d_in[11];
    const float* bg   = (const float*)d_in[12];
    float* out = (float*)d_out;

    const int* src = ei;
    const int* dst = ei + NE;

    // workspace layout (16B aligned), ~34.1 MB
    char* ws = (char*)d_ws;
    int* cnt4 = (int*)(ws + 0);                               //    320,000 B
    unsigned int* s_p = (unsigned int*)(ws + 320128);         // 12,800,000 B
    unsigned short* XH  = (unsigned short*)(ws + 13120128);   // 10,240,000 B
    unsigned short* AGG = (unsigned short*)(ws + 23360128);   // 10,240,000 B
    unsigned short* Wsz = (unsigned short*)(ws + 33600128);   //    524,288 B
    float* bias = (float*)(ws + 34124416);                    //      2,048 B

    hipMemsetAsync(cnt4, 0, NN * 4 * sizeof(int), stream);
    prep_fill_kernel<<<5120, 256, 0, stream>>>(src, dst, ew, cnt4, s_p,
                                               (const float4*)X, (const float4*)H,
                                               (unsigned int*)XH,
                                               Wx_l, Wx_r, Wh_l, Wh_r,
                                               bx, bh, bg, Wsz, bias);
    aggregate_kernel<<<NN / 4, 256, 0, stream>>>(XH, cnt4, s_p, AGG);
    gemm_lstm_kernel<<<626, 256, 0, stream>>>(XH, AGG, Wsz, bias, wc, C, out);
}

// Round 13
// 196.884 us; speedup vs baseline: 1.0190x; 1.0179x over previous
//
#include <hip/hip_runtime.h>
#include <math.h>

#define NN 20000
#define NE 640000
#define D  128
#define NSLICE 2500        // NN / 8 XCDs
#define SUBSEG 40          // per-(node, src-quartile) sub-segment depth
#define SEGSTRIDE 160      // 4 * SUBSEG entries per node
#define CHUNK 1000         // edges per fill chunk (640*1000 = NE)

typedef __attribute__((ext_vector_type(8))) short short8;
typedef __attribute__((ext_vector_type(4))) float floatx4;

static __device__ __forceinline__ unsigned short f2bf(float f) {
    union { float f; unsigned int u; } v; v.f = f;
    unsigned int u = v.u;
    u += 0x7fff + ((u >> 16) & 1);   // round-to-nearest-even
    return (unsigned short)(u >> 16);
}
static __device__ __forceinline__ unsigned int pack2bf(float a, float b) {
    return (unsigned int)f2bf(a) | ((unsigned int)f2bf(b) << 16);
}
static __device__ __forceinline__ float bf_lo(unsigned int u) {
    union { unsigned int i; float f; } v; v.i = u << 16; return v.f;
}
static __device__ __forceinline__ float bf_hi(unsigned int u) {
    union { unsigned int i; float f; } v; v.i = u & 0xffff0000u; return v.f;
}
static __device__ __forceinline__ float sigm(float x) { return 1.f / (1.f + __expf(-x)); }
static __device__ __forceinline__ float tanhx(float x) { return 1.f - 2.f / (__expf(2.f * x) + 1.f); }

// Fused prep + CSR fill (R10 bytes — control). Src-quartile-binned bump
// allocation (q = src/5000, SUBSEG deep); X/H bf16 pack; coalesced weight
// transpose; bias fuse; XCD-sliced fill.
// Wsz layout (shorts): idx = ci*16384 + jg*4096 + col*8 + off, k = ci*32+jg*8+off.
__global__ void __launch_bounds__(256)
prep_fill_kernel(const int* __restrict__ src, const int* __restrict__ dst,
                 const float* __restrict__ ew, int* __restrict__ cnt4,
                 unsigned int* __restrict__ s_p,
                 const float4* __restrict__ X4, const float4* __restrict__ H4,
                 unsigned int* __restrict__ XH32,
                 const float* __restrict__ Wx_l, const float* __restrict__ Wx_r,
                 const float* __restrict__ Wh_l, const float* __restrict__ Wh_r,
                 const float* __restrict__ bx, const float* __restrict__ bh,
                 const float* __restrict__ bg,
                 unsigned short* __restrict__ Wsz, float* __restrict__ bias) {
    int tid = threadIdx.x, b = blockIdx.x;       // 5120 blocks x 256 threads

    int chunk = b >> 3, s = b & 7;
    int lo = s * NSLICE, hi = lo + NSLICE;
    int4 d4, sr4; float4 w4;
    bool fill = (tid < 250);
    if (fill) {
        int e0 = chunk * CHUNK + tid * 4;
        d4  = *(const int4*)(dst + e0);
        sr4 = *(const int4*)(src + e0);
        w4  = *(const float4*)(ew + e0);
    }

    if (b < 2560) {
        int t = b * 256 + tid;
        if (t < NE) {
            float4 x = X4[t];
            float4 h = H4[t];
            int n = t >> 5, q = t & 31;
            unsigned int* row = XH32 + n * 128;
            row[2 * q]          = pack2bf(x.x, x.y);
            row[2 * q + 1]      = pack2bf(x.z, x.w);
            row[64 + 2 * q]     = pack2bf(h.x, h.y);
            row[64 + 2 * q + 1] = pack2bf(h.z, h.w);
        }
    } else if (b < 2816) {
        int t = (b - 2560) * 256 + tid;      // < 65536
        int row = t >> 5;                    // row = g*512 + k
        int g = row >> 9, k = row & 511;
        int o = (t & 31) * 4;
        const float* Wb; int kk;
        if (k < 128)      { Wb = Wx_l; kk = k; }
        else if (k < 256) { Wb = Wx_r; kk = k - 128; }
        else if (k < 384) { Wb = Wh_l; kk = k - 256; }
        else              { Wb = Wh_r; kk = k - 384; }
        float4 w = *(const float4*)(Wb + g * 16384 + kk * 128 + o);
        int ci = k >> 5, jg = (k >> 3) & 3, off = k & 7;
        unsigned short* wp = Wsz + ci * 16384 + jg * 4096 + (g * 128 + o) * 8 + off;
        wp[0]  = f2bf(w.x);
        wp[8]  = f2bf(w.y);
        wp[16] = f2bf(w.z);
        wp[24] = f2bf(w.w);
        if (k == 0) {
            int j0 = g * 128 + o;
#pragma unroll
            for (int i = 0; i < 4; ++i)
                bias[j0 + i] = bx[j0 + i] + bh[j0 + i] + bg[j0 + i];
        }
    }

    if (fill) {
        int dv[4] = {d4.x, d4.y, d4.z, d4.w};
        int sv[4] = {sr4.x, sr4.y, sr4.z, sr4.w};
        float wv[4] = {w4.x, w4.y, w4.z, w4.w};
#pragma unroll
        for (int k = 0; k < 4; ++k) {
            int d = dv[k];
            if (d >= lo && d < hi) {
                int q = (int)((unsigned)sv[k] / 5000u);   // src window 0..3
                int p = atomicAdd(&cnt4[d * 4 + q], 1);
                if (p < SUBSEG)
                    s_p[d * SEGSTRIDE + q * SUBSEG + p] =
                        (unsigned int)sv[k] | ((unsigned int)f2bf(wv[k]) << 16);
            }
        }
    }
}

// Aggregation (R10 bytes — control; R12's paired-uint4 variant reverted:
// measured neutral-to-negative). 4 source-window passes (2.56 MB window
// fits per-XCD L2), in-register partials, scalarized seg/weight/address
// via readfirstlane(n), full-row 8 B/lane gathers.
__global__ void __launch_bounds__(256)
aggregate_kernel(const uint2* __restrict__ XH64,
                 const int* __restrict__ cnt4,
                 const unsigned int* __restrict__ s_p,
                 uint2* __restrict__ AGG64) {
    int wv = threadIdx.x >> 6, lane = threadIdx.x & 63;
    int b = blockIdx.x;                 // 0..4999
    int s = b & 7, j = b >> 3;          // j: 0..624
    int n = __builtin_amdgcn_readfirstlane(s * NSLICE + j * 4 + wv);
    int c0 = cnt4[n * 4 + 0];           // uniform -> scalar loads
    int c1 = cnt4[n * 4 + 1];
    int c2 = cnt4[n * 4 + 2];
    int c3 = cnt4[n * 4 + 3];
    int deg = c0 + c1 + c2 + c3;
    const unsigned int* segbase = s_p + (size_t)n * SEGSTRIDE;
    float a0 = 0.f, a1 = 0.f, a2 = 0.f, a3 = 0.f;

#pragma unroll
    for (int p = 0; p < 4; ++p) {
        int c = (p == 0) ? c0 : (p == 1) ? c1 : (p == 2) ? c2 : c3;
        int m = (c < SUBSEG) ? c : SUBSEG;
        const unsigned int* seg = segbase + p * SUBSEG;
        int i = 0;
        for (; i + 8 <= m; i += 8) {
            unsigned int e[8];
            uint2 u[8];
#pragma unroll
            for (int k = 0; k < 8; ++k) e[k] = seg[i + k];   // scalar
#pragma unroll
            for (int k = 0; k < 8; ++k)
                u[k] = XH64[(size_t)(e[k] & 0xffff) * 64 + lane];
#pragma unroll
            for (int k = 0; k < 8; ++k) {
                float w = __int_as_float(e[k] & 0xffff0000u);
                a0 += bf_lo(u[k].x) * w;
                a1 += bf_hi(u[k].x) * w;
                a2 += bf_lo(u[k].y) * w;
                a3 += bf_hi(u[k].y) * w;
            }
        }
        for (; i + 4 <= m; i += 4) {
            unsigned int e[4];
            uint2 u[4];
#pragma unroll
            for (int k = 0; k < 4; ++k) e[k] = seg[i + k];
#pragma unroll
            for (int k = 0; k < 4; ++k)
                u[k] = XH64[(size_t)(e[k] & 0xffff) * 64 + lane];
#pragma unroll
            for (int k = 0; k < 4; ++k) {
                float w = __int_as_float(e[k] & 0xffff0000u);
                a0 += bf_lo(u[k].x) * w;
                a1 += bf_hi(u[k].x) * w;
                a2 += bf_lo(u[k].y) * w;
                a3 += bf_hi(u[k].y) * w;
            }
        }
        for (; i < m; ++i) {
            unsigned int e = seg[i];
            float w = __int_as_float(e & 0xffff0000u);
            uint2 u = XH64[(size_t)(e & 0xffff) * 64 + lane];
            a0 += bf_lo(u.x) * w;
            a1 += bf_hi(u.x) * w;
            a2 += bf_lo(u.y) * w;
            a3 += bf_hi(u.y) * w;
        }
    }

    float inv = (deg > 0) ? 1.0f / (float)deg : 1.0f;
    uint2 r;
    r.x = pack2bf(a0 * inv, a1 * inv);
    r.y = pack2bf(a2 * inv, a3 * inv);
    AGG64[(size_t)n * 64 + lane] = r;
}

// R13 GEMM + peephole-LSTM: R7 no-LDS structure + DISTANCE-2 register
// prefetch (T4 counted-wait mechanism in plain HIP).
// Diagnosis: every gemm this session (LDS dbuf / direct-L2 / one-shot
// panel) used distance-1 prefetch -> the register copy before the next
// iter's MFMAs forces an effective vmcnt(0) drain every K-iter; MfmaUtil
// 8.4% = pure latency exposure (73% of cycles issue nothing).
// Fix: even/odd NAMED register sets (no runtime indexing — scratch rule),
// fully unrolled; iter i consumes set i&1 and reloads that set for i+2.
// Loads return in order, so the compiler's wait before iter i+1's MFMAs
// covers only the batch issued at i-1 — the batch issued at i stays in
// flight across it (counted vmcnt, not drain-0). ~145 VGPR -> 3 waves/SIMD.
// 1250 blocks = 625 m-tiles x 2 col-halves; K-chunk order aggX,X,aggH,H
// matches Wsz ci=0..15; in-register LSTM epilogue.
#define LOADSET(S, j) do {                                                   \
        int kn_ = (j) * 32;                                                  \
        const unsigned short* ab_ = (kn_ & 128) ? XH : AGG;                  \
        int aoff_ = (kn_ & 127) | ((kn_ & 256) >> 1);                        \
        const unsigned short* ar_ = ab_ + (size_t)(m0 + lm) * 256 + aoff_ + lq * 8; \
        a0_##S = *(const short8*)ar_;                                        \
        a1_##S = *(const short8*)(ar_ + 16 * 256);                           \
        const unsigned short* wb_ = wbase + (j) * 16384;                     \
        b0_##S = *(const short8*)(wb_);                                      \
        b1_##S = *(const short8*)(wb_ + 1024);                               \
        b2_##S = *(const short8*)(wb_ + 2048);                               \
        b3_##S = *(const short8*)(wb_ + 3072);                               \
    } while (0)

#define MFMA8(S) do {                                                        \
        acc[0][0] = __builtin_amdgcn_mfma_f32_16x16x32_bf16(a0_##S, b0_##S, acc[0][0], 0, 0, 0); \
        acc[1][0] = __builtin_amdgcn_mfma_f32_16x16x32_bf16(a1_##S, b0_##S, acc[1][0], 0, 0, 0); \
        acc[0][1] = __builtin_amdgcn_mfma_f32_16x16x32_bf16(a0_##S, b1_##S, acc[0][1], 0, 0, 0); \
        acc[1][1] = __builtin_amdgcn_mfma_f32_16x16x32_bf16(a1_##S, b1_##S, acc[1][1], 0, 0, 0); \
        acc[0][2] = __builtin_amdgcn_mfma_f32_16x16x32_bf16(a0_##S, b2_##S, acc[0][2], 0, 0, 0); \
        acc[1][2] = __builtin_amdgcn_mfma_f32_16x16x32_bf16(a1_##S, b2_##S, acc[1][2], 0, 0, 0); \
        acc[0][3] = __builtin_amdgcn_mfma_f32_16x16x32_bf16(a0_##S, b3_##S, acc[0][3], 0, 0, 0); \
        acc[1][3] = __builtin_amdgcn_mfma_f32_16x16x32_bf16(a1_##S, b3_##S, acc[1][3], 0, 0, 0); \
    } while (0)

__global__ void __launch_bounds__(256)
gemm_lstm_kernel(const unsigned short* __restrict__ XH,
                 const unsigned short* __restrict__ AGG,
                 const unsigned short* __restrict__ Wsz,
                 const float* __restrict__ bias,
                 const float* __restrict__ wc,
                 const float* __restrict__ C,
                 float* __restrict__ out) {
    int tid = threadIdx.x;
    int wv = tid >> 6, lane = tid & 63;
    int lm = lane & 15, lq = lane >> 4;
    int bid = blockIdx.x;               // 1250 = 625 m-tiles x 2 halves
    int m0 = (bid >> 1) * 32;
    int hb = (bid & 1) * 512;           // half-offset in shorts (64 cols * 8)

    floatx4 acc[2][4];
#pragma unroll
    for (int mt = 0; mt < 2; ++mt)
#pragma unroll
        for (int g = 0; g < 4; ++g) acc[mt][g] = (floatx4)(0.f);

    // B base: col = g*128 + hb/8 + wv*16 + lm, k-group jg = lq
    const unsigned short* wbase = Wsz + hb + lq * 4096 + ((wv << 4) + lm) * 8;

    // even/odd register sets, distance-2 pipeline
    short8 a0_e, a1_e, b0_e, b1_e, b2_e, b3_e;
    short8 a0_o, a1_o, b0_o, b1_o, b2_o, b3_o;
    LOADSET(e, 0);
    LOADSET(o, 1);

#pragma unroll
    for (int t = 0; t < 8; ++t) {
        MFMA8(e);                       // consume even set (iter 2t)
        if (2 * t + 2 < 16) LOADSET(e, 2 * t + 2);
        MFMA8(o);                       // consume odd set (iter 2t+1)
        if (2 * t + 3 < 16) LOADSET(o, 2 * t + 3);
    }

    // ---- LSTM epilogue (in-register) ----
    int cg0 = (hb >> 3) + (wv << 4) + lm;
    float bG[4], wP[3];
#pragma unroll
    for (int g = 0; g < 4; ++g) bG[g] = bias[(g << 7) + cg0];
#pragma unroll
    for (int j = 0; j < 3; ++j) wP[j] = wc[j * 128 + cg0];

#pragma unroll
    for (int mt = 0; mt < 2; ++mt)
#pragma unroll
        for (int r = 0; r < 4; ++r) {
            int row = m0 + mt * 16 + lq * 4 + r;   // 625*32 == NN exact, no guard
            float c = C[(size_t)row * D + cg0];
            float pi = acc[mt][0][r] + bG[0] + wP[0] * c;
            float pf = acc[mt][1][r] + bG[1] + wP[1] * c;
            float pt = acc[mt][2][r] + bG[2];
            float po = acc[mt][3][r] + bG[3];
            float I = sigm(pi);
            float F = sigm(pf);
            float T = tanhx(pt);
            float cn = F * c + I * T;
            float O = sigm(po + wP[2] * cn);
            out[(size_t)row * D + cg0] = O * tanhx(cn);
            out[(size_t)NN * D + (size_t)row * D + cg0] = cn;
        }
}

extern "C" void kernel_launch(void* const* d_in, const int* in_sizes, int n_in,
                              void* d_out, int out_size, void* d_ws, size_t ws_size,
                              hipStream_t stream) {
    const float* X  = (const float*)d_in[0];
    const int* ei   = (const int*)d_in[1];
    const float* ew = (const float*)d_in[2];
    const float* H  = (const float*)d_in[3];
    const float* C  = (const float*)d_in[4];
    const float* Wx_l = (const float*)d_in[5];
    const float* Wx_r = (const float*)d_in[6];
    const float* bx   = (const float*)d_in[7];
    const float* Wh_l = (const float*)d_in[8];
    const float* Wh_r = (const float*)d_in[9];
    const float* bh   = (const float*)d_in[10];
    const float* wc   = (const float*)d_in[11];
    const float* bg   = (const float*)d_in[12];
    float* out = (float*)d_out;

    const int* src = ei;
    const int* dst = ei + NE;

    // workspace layout (16B aligned), ~34.1 MB
    char* ws = (char*)d_ws;
    int* cnt4 = (int*)(ws + 0);                               //    320,000 B
    unsigned int* s_p = (unsigned int*)(ws + 320128);         // 12,800,000 B
    unsigned short* XH  = (unsigned short*)(ws + 13120128);   // 10,240,000 B
    unsigned short* AGG = (unsigned short*)(ws + 23360128);   // 10,240,000 B
    unsigned short* Wsz = (unsigned short*)(ws + 33600128);   //    524,288 B
    float* bias = (float*)(ws + 34124416);                    //      2,048 B

    hipMemsetAsync(cnt4, 0, NN * 4 * sizeof(int), stream);
    prep_fill_kernel<<<5120, 256, 0, stream>>>(src, dst, ew, cnt4, s_p,
                                               (const float4*)X, (const float4*)H,
                                               (unsigned int*)XH,
                                               Wx_l, Wx_r, Wh_l, Wh_r,
                                               bx, bh, bg, Wsz, bias);
    aggregate_kernel<<<NN / 4, 256, 0, stream>>>((const uint2*)XH, cnt4, s_p,
                                                 (uint2*)AGG);
    gemm_lstm_kernel<<<1250, 256, 0, stream>>>(XH, AGG, Wsz, bias, wc, C, out);
}